// Round 12
// baseline (72.610 us; speedup 1.0000x reference)
//
#include <hip/hip_runtime.h>
#include <hip/hip_bf16.h>

#define B 16
#define S 2048
#define VOCAB 32000
#define D_EMB 256
#define D_MODEL 512
#define LN_EPS 1e-5f

using bf16x8 = __attribute__((ext_vector_type(8))) short;
using f32x4  = __attribute__((ext_vector_type(4))) float;

static __device__ __forceinline__ unsigned short f2bf(float f) {
    __hip_bfloat16 h = __float2bfloat16(f);   // RNE
    return *reinterpret_cast<unsigned short*>(&h);
}

static __device__ __forceinline__ bf16x8 pack8(f32x4 v0, f32x4 v1) {
    union { unsigned short us[8]; bf16x8 v; } pk;
    pk.us[0] = f2bf(v0.x); pk.us[1] = f2bf(v0.y);
    pk.us[2] = f2bf(v0.z); pk.us[3] = f2bf(v0.w);
    pk.us[4] = f2bf(v1.x); pk.us[5] = f2bf(v1.y);
    pk.us[6] = f2bf(v1.z); pk.us[7] = f2bf(v1.w);
    return pk.v;
}

// ---------------------------------------------------------------------------
// Kernel A (MFMA) — EXACT R5 form (measured: 23.1 µs ≈ its 21 µs Wb floor).
// ---------------------------------------------------------------------------
__global__ __launch_bounds__(256) void wk_mfma(
    const float* __restrict__ Wb,
    const float* __restrict__ king_table,
    const int* __restrict__ king_id,
    unsigned short* __restrict__ Wk)
{
    const int t    = threadIdx.x;
    const int lane = t & 63;
    const int wave = t >> 6;
    const int lr   = lane & 15;     // b index (B-frag col) / row index (A-frag)
    const int kg   = lane >> 4;     // k-group

    const int kid = king_id[lr];
    const float* kp = king_table + (size_t)kid * D_EMB + kg * 8;
    bf16x8 bemb[8];
#pragma unroll
    for (int step = 0; step < 8; ++step) {
        f32x4 v0 = *(const f32x4*)(kp + step * 32);
        f32x4 v1 = *(const f32x4*)(kp + step * 32 + 4);
        bemb[step] = pack8(v0, v1);
    }

    const int rbase = (blockIdx.x * 4 + wave) * 64;

#pragma unroll
    for (int mf = 0; mf < 4; ++mf) {
        const float* arow = Wb + (size_t)(rbase + mf * 16 + lr) * D_EMB + kg * 8;
        f32x4 acc = {};
#pragma unroll
        for (int step = 0; step < 8; ++step) {
            f32x4 v0 = *(const f32x4*)(arow + step * 32);
            f32x4 v1 = *(const f32x4*)(arow + step * 32 + 4);
            acc = __builtin_amdgcn_mfma_f32_16x16x32_bf16(
                pack8(v0, v1), bemb[step], acc, 0, 0, 0);
        }
        union { unsigned short us[4]; uint2 q; } st;
        st.us[0] = f2bf(acc[0]); st.us[1] = f2bf(acc[1]);
        st.us[2] = f2bf(acc[2]); st.us[3] = f2bf(acc[3]);
        *(uint2*)(Wk + (size_t)lr * (D_MODEL * D_EMB) + rbase + mf * 16 + kg * 4) = st.q;
    }
}

// ---------------------------------------------------------------------------
// Kernel B (MFMA) — half-tile read/write overlap pipeline:
//   stage H0(32 rows) -> bar -> issue H1 gather (regs) ->
//   K-loop H0 (M_rep=2, acc 32 VGPR) -> land H1 regs->LDS (disjoint rows,
//   no barrier) -> LN+store H0 -> K-loop H1 (NO barrier after store issue:
//   H0's write burst retires under H1's compute + Wk L2 reads) ->
//   LN+store H1.
// Keeps XCD decode (R11) + __launch_bounds__(512,4), grid 512, TSB=64.
// Cost: Wk wave-slice read twice per block (L2-hot; falsified as bottleneck
// by R11). Gain: read burst / write burst overlap inside each block.
// ---------------------------------------------------------------------------
#define TSB 64
#define HROWS 32

__global__ __launch_bounds__(512, 4) void gemm_ln_mfma(
    const int* __restrict__ seq,
    const int* __restrict__ king_id,
    const float* __restrict__ token_tables,
    const unsigned short* __restrict__ Wk,
    const float* __restrict__ bb,
    const float* __restrict__ gamma,
    const float* __restrict__ beta,
    float* __restrict__ out)
{
    __shared__ unsigned short tokL[TSB][264];   // 64 x (256+8 pad) bf16
    __shared__ float red_sum[8][HROWS];
    __shared__ float red_sq[8][HROWS];
    __shared__ float stats[2][HROWS];           // [0]=mean, [1]=rstd

    // ---- XCD-aware decode (R11): same-b blocks pin to one XCD ----
    const int id   = blockIdx.x;
    const int xcd  = id & 7;
    const int kk   = id >> 3;              // 0..63
    const int b    = xcd * 2 + (kk >> 5);  // 2 batches per XCD
    const int tile = kk & 31;

    const int s0   = tile * TSB;
    const int t    = threadIdx.x;
    const int lane = t & 63;
    const int wave = t >> 6;
    const int lr   = lane & 15;     // frag row/col index
    const int kg   = lane >> 4;     // k-group (0..3)

    const int kb = king_id[b];
    const float* ttab = token_tables + (size_t)kb * VOCAB * D_EMB;

    // staging geometry: 32 rows/half, 16 thr/row, 16 floats (64 B) each
    const int srow = t >> 4;            // 0..31
    const int sck  = (t & 15) * 16;     // 0..240
    const int tok0 = seq[b * S + s0 + srow];
    const int tok1 = seq[b * S + s0 + HROWS + srow];
    const float* src0 = ttab + (size_t)tok0 * D_EMB + sck;
    const float* src1 = ttab + (size_t)tok1 * D_EMB + sck;

    // ---- stage H0 ----
    {
        f32x4 v0 = *(const f32x4*)(src0 + 0);
        f32x4 v1 = *(const f32x4*)(src0 + 4);
        f32x4 v2 = *(const f32x4*)(src0 + 8);
        f32x4 v3 = *(const f32x4*)(src0 + 12);
        *(bf16x8*)&tokL[srow][sck]     = pack8(v0, v1);
        *(bf16x8*)&tokL[srow][sck + 8] = pack8(v2, v3);
    }
    __syncthreads();

    // ---- issue H1 gather early (T14): held in regs through K-loop H0 ----
    f32x4 h0 = *(const f32x4*)(src1 + 0);
    f32x4 h1 = *(const f32x4*)(src1 + 4);
    f32x4 h2 = *(const f32x4*)(src1 + 8);
    f32x4 h3 = *(const f32x4*)(src1 + 12);

    // ---- fragment pointers / LN params (hoisted) ----
    const int m0 = wave * 64;
    const uint4* bptr[4];
    float bbv[4], gv[4], bv[4];
#pragma unroll
    for (int nf = 0; nf < 4; ++nf) {
        int col = m0 + nf * 16 + lr;
        bptr[nf] = (const uint4*)(Wk + ((size_t)(b * D_MODEL + col)) * D_EMB + kg * 8);
        bbv[nf] = bb[col];
        gv[nf]  = gamma[col];
        bv[nf]  = beta[col];
    }

    f32x4 acc[2][4] = {};

    // ---- K-loop H0 (rows 0-31, M_rep=2) ----
#pragma unroll
    for (int step = 0; step < 8; ++step) {
        bf16x8 af[2], bfr[4];
#pragma unroll
        for (int mf = 0; mf < 2; ++mf) {
            uint4 q = *(const uint4*)&tokL[mf * 16 + lr][step * 32 + kg * 8];
            af[mf] = __builtin_bit_cast(bf16x8, q);
        }
#pragma unroll
        for (int nf = 0; nf < 4; ++nf) {
            uint4 q = bptr[nf][step * 4];
            bfr[nf] = __builtin_bit_cast(bf16x8, q);
        }
#pragma unroll
        for (int mf = 0; mf < 2; ++mf)
#pragma unroll
            for (int nf = 0; nf < 4; ++nf)
                acc[mf][nf] = __builtin_amdgcn_mfma_f32_16x16x32_bf16(
                    af[mf], bfr[nf], acc[mf][nf], 0, 0, 0);
    }

    // ---- land H1 into LDS rows 32-63 (disjoint from H0 reads) ----
    *(bf16x8*)&tokL[HROWS + srow][sck]     = pack8(h0, h1);
    *(bf16x8*)&tokL[HROWS + srow][sck + 8] = pack8(h2, h3);
    // visibility for K-loop H1 is guaranteed by the LN-H0 barriers below

    // ---- LN + store H0 ----
#pragma unroll
    for (int mf = 0; mf < 2; ++mf) {
#pragma unroll
        for (int r = 0; r < 4; ++r) {
            float sum = 0.0f, sq = 0.0f;
#pragma unroll
            for (int nf = 0; nf < 4; ++nf) {
                float v = acc[mf][nf][r] + bbv[nf];
                acc[mf][nf][r] = v;
                sum += v;
                sq  += v * v;
            }
#pragma unroll
            for (int off = 1; off < 16; off <<= 1) {
                sum += __shfl_xor(sum, off);
                sq  += __shfl_xor(sq, off);
            }
            if (lr == 0) {
                int row = mf * 16 + kg * 4 + r;
                red_sum[wave][row] = sum;
                red_sq[wave][row]  = sq;
            }
        }
    }
    __syncthreads();
    if (t < HROWS) {
        float s = 0.0f, q = 0.0f;
#pragma unroll
        for (int w = 0; w < 8; ++w) { s += red_sum[w][t]; q += red_sq[w][t]; }
        float mean = s * (1.0f / D_MODEL);
        float var  = q * (1.0f / D_MODEL) - mean * mean;
        stats[0][t] = mean;
        stats[1][t] = rsqrtf(var + LN_EPS);
    }
    __syncthreads();
#pragma unroll
    for (int mf = 0; mf < 2; ++mf) {
#pragma unroll
        for (int r = 0; r < 4; ++r) {
            int row = mf * 16 + kg * 4 + r;
            float mean = stats[0][row];
            float rstd = stats[1][row];
            float* op = out + ((size_t)b * S + s0 + row) * D_MODEL + m0 + lr;
#pragma unroll
            for (int nf = 0; nf < 4; ++nf)
                op[nf * 16] = (acc[mf][nf][r] - mean) * rstd * gv[nf] + bv[nf];
        }
    }
    // NOTE: no barrier here — H0 stores retire while H1 computes.

    // ---- K-loop H1 (rows 32-63) ----
#pragma unroll
    for (int mf = 0; mf < 2; ++mf)
#pragma unroll
        for (int nf = 0; nf < 4; ++nf)
            acc[mf][nf] = (f32x4){};

#pragma unroll
    for (int step = 0; step < 8; ++step) {
        bf16x8 af[2], bfr[4];
#pragma unroll
        for (int mf = 0; mf < 2; ++mf) {
            uint4 q = *(const uint4*)&tokL[HROWS + mf * 16 + lr][step * 32 + kg * 8];
            af[mf] = __builtin_bit_cast(bf16x8, q);
        }
#pragma unroll
        for (int nf = 0; nf < 4; ++nf) {
            uint4 q = bptr[nf][step * 4];       // L2-hot re-read
            bfr[nf] = __builtin_bit_cast(bf16x8, q);
        }
#pragma unroll
        for (int mf = 0; mf < 2; ++mf)
#pragma unroll
            for (int nf = 0; nf < 4; ++nf)
                acc[mf][nf] = __builtin_amdgcn_mfma_f32_16x16x32_bf16(
                    af[mf], bfr[nf], acc[mf][nf], 0, 0, 0);
    }

    // ---- LN + store H1 ----
#pragma unroll
    for (int mf = 0; mf < 2; ++mf) {
#pragma unroll
        for (int r = 0; r < 4; ++r) {
            float sum = 0.0f, sq = 0.0f;
#pragma unroll
            for (int nf = 0; nf < 4; ++nf) {
                float v = acc[mf][nf][r] + bbv[nf];
                acc[mf][nf][r] = v;
                sum += v;
                sq  += v * v;
            }
#pragma unroll
            for (int off = 1; off < 16; off <<= 1) {
                sum += __shfl_xor(sum, off);
                sq  += __shfl_xor(sq, off);
            }
            if (lr == 0) {
                int row = mf * 16 + kg * 4 + r;
                red_sum[wave][row] = sum;
                red_sq[wave][row]  = sq;
            }
        }
    }
    __syncthreads();
    if (t < HROWS) {
        float s = 0.0f, q = 0.0f;
#pragma unroll
        for (int w = 0; w < 8; ++w) { s += red_sum[w][t]; q += red_sq[w][t]; }
        float mean = s * (1.0f / D_MODEL);
        float var  = q * (1.0f / D_MODEL) - mean * mean;
        stats[0][t] = mean;
        stats[1][t] = rsqrtf(var + LN_EPS);
    }
    __syncthreads();
#pragma unroll
    for (int mf = 0; mf < 2; ++mf) {
#pragma unroll
        for (int r = 0; r < 4; ++r) {
            int row = mf * 16 + kg * 4 + r;
            float mean = stats[0][row];
            float rstd = stats[1][row];
            float* op = out + ((size_t)b * S + s0 + HROWS + row) * D_MODEL + m0 + lr;
#pragma unroll
            for (int nf = 0; nf < 4; ++nf)
                op[nf * 16] = (acc[mf][nf][r] - mean) * rstd * gv[nf] + bv[nf];
        }
    }
}

// ---------------------------------------------------------------------------
extern "C" void kernel_launch(void* const* d_in, const int* in_sizes, int n_in,
                              void* d_out, int out_size, void* d_ws, size_t ws_size,
                              hipStream_t stream)
{
    const int*   seq          = (const int*)d_in[0];
    const int*   king_id      = (const int*)d_in[1];
    const float* token_tables = (const float*)d_in[2];
    const float* Wb           = (const float*)d_in[3];
    const float* bb           = (const float*)d_in[4];
    const float* king_table   = (const float*)d_in[5];
    const float* gamma        = (const float*)d_in[6];
    const float* beta         = (const float*)d_in[7];
    float* out = (float*)d_out;

    unsigned short* Wk = (unsigned short*)d_ws;   // B*D_MODEL*D_EMB bf16 = 4 MB

    wk_mfma<<<dim3((D_MODEL * D_EMB) / 256), dim3(256), 0, stream>>>(
        Wb, king_table, king_id, Wk);
    gemm_ln_mfma<<<dim3(S / TSB * B), dim3(512), 0, stream>>>(
        seq, king_id, token_tables, Wk, bb, gamma, beta, out);
}